// Round 1
// baseline (219.903 us; speedup 1.0000x reference)
//
#include <hip/hip_runtime.h>
#include <math.h>

#define DEV __device__ __forceinline__

DEV float rcp_fast(float x) { return __builtin_amdgcn_rcpf(x); }
DEV float rsq_fast(float x) { return __builtin_amdgcn_rsqf(x); }

// packed upper-triangle index for NxN symmetric, requires i<=j
__host__ __device__ constexpr int TI(int n, int i, int j) {
  return n * i - (i * (i - 1)) / 2 + (j - i);
}

template <int N>
DEV float& sym_at(float (&a)[N * (N + 1) / 2], int i, int j) {
  return (i <= j) ? a[TI(N, i, j)] : a[TI(N, j, i)];
}

// Cyclic Jacobi eigenvalue iteration on packed upper triangle (values only).
// Fully unrolled p/q/i loops -> all indices compile-time -> stays in VGPRs.
template <int N, int SWEEPS>
DEV void jacobi_sweeps(float (&a)[N * (N + 1) / 2]) {
  float tr = 0.0f;
#pragma unroll
  for (int i = 0; i < N; ++i) tr += a[TI(N, i, i)];
  const float thr = fabsf(tr) * 1e-8f + 1e-30f;  // trace is rotation-invariant
  for (int sw = 0; sw < SWEEPS; ++sw) {
#pragma unroll
    for (int p = 0; p < N - 1; ++p) {
#pragma unroll
      for (int q = p + 1; q < N; ++q) {
        float apq = a[TI(N, p, q)];
        if (fabsf(apq) > thr) {
          float app = a[TI(N, p, p)];
          float aqq = a[TI(N, q, q)];
          float h  = aqq - app;
          float tw = apq + apq;
          // t = sgn(h) * 2*apq / (|h| + sqrt(h^2 + 4 apq^2))  (NR convention)
          float den = fabsf(h) + sqrtf(fmaf(h, h, tw * tw));
          float t = tw * rcp_fast(den);
          t = (h < 0.0f) ? -t : t;
          float c = rsq_fast(fmaf(t, t, 1.0f));
          float s = t * c;
          float tau = s * rcp_fast(1.0f + c);
          a[TI(N, p, p)] = fmaf(-t, apq, app);
          a[TI(N, q, q)] = fmaf( t, apq, aqq);
          a[TI(N, p, q)] = 0.0f;
#pragma unroll
          for (int i = 0; i < N; ++i) {
            if (i != p && i != q) {
              float g  = sym_at<N>(a, i, p);
              float hh = sym_at<N>(a, i, q);
              sym_at<N>(a, i, p) = fmaf(-s, fmaf( tau, g, hh), g);
              sym_at<N>(a, i, q) = fmaf( s, fmaf(-tau, hh, g), hh);
            }
          }
        }
      }
    }
  }
}

// entropy of eigenvalue distribution, mirroring reference EPS placement:
// s_sq = lam + 1e-10 ; p = s_sq/sum ; H = -sum p*log(p + 1e-10)
template <int N>
DEV float entropy_of(const float (&a)[N * (N + 1) / 2]) {
  float lam[N];
  float sum = 0.0f;
#pragma unroll
  for (int i = 0; i < N; ++i) {
    float l = fmaxf(a[TI(N, i, i)], 0.0f) + 1e-10f;
    lam[i] = l;
    sum += l;
  }
  float inv = 1.0f / sum;
  float H = 0.0f;
#pragma unroll
  for (int i = 0; i < N; ++i) {
    float p = lam[i] * inv;
    H = fmaf(p, __logf(p + 1e-10f), H);
  }
  return -H;
}

// --- cross-lane reduction with distribution -------------------------------
// cur[e] per lane = partial of entry e. After: return value on lane l is the
// full 64-lane sum of entry l. Invariant at step d: cur[i] holds entry
// e = (i<<d) | (lane & ((1<<d)-1)).
DEV float reduce_dist_64(float (&cur)[64], int lane) {
#pragma unroll
  for (int d = 0; d < 6; ++d) {
    const int dist = 1 << d;
    const int up = (lane >> d) & 1;
#pragma unroll
    for (int m = 0; m < (64 >> (d + 1)); ++m) {
      float snd = up ? cur[2 * m]     : cur[2 * m + 1];
      float kp  = up ? cur[2 * m + 1] : cur[2 * m];
      float r = __shfl_xor(snd, dist, 64);
      cur[m] = kp + r;
    }
  }
  return cur[0];
}

// 32 entries over 64 lanes: result = full sum of entry (lane & 31),
// duplicated on lanes l and l^32.
DEV float reduce_dist_32(float (&cur)[32], int lane) {
#pragma unroll
  for (int d = 0; d < 5; ++d) {
    const int dist = 1 << d;
    const int up = (lane >> d) & 1;
#pragma unroll
    for (int m = 0; m < (32 >> (d + 1)); ++m) {
      float snd = up ? cur[2 * m]     : cur[2 * m + 1];
      float kp  = up ? cur[2 * m + 1] : cur[2 * m];
      float r = __shfl_xor(snd, dist, 64);
      cur[m] = kp + r;
    }
  }
  float v = cur[0];
  v += __shfl_xor(v, 32, 64);
  return v;
}

// --- Phase 1: correlation matrices ----------------------------------------
// One wave per batch. Lane l owns k in [4l, 4l+4) of every site row.
// Output layout: cmat[e * 8192 + b], e in [0,96):
//   e in [0,64):  C_whole[i][j], e = i*8+j   (A=sites 0..7, B=sites 8..15)
//   e in [64,80): C_left [i][j], e-64 = i*4+j (A=0..3,  B=4..7)
//   e in [80,96): C_right[i][j], e-80 = i*4+j (A=8..11, B=12..15)
__global__ __launch_bounds__(64) void corr_kernel(
    const float* __restrict__ sites, float* __restrict__ cmat) {
  const int b = blockIdx.x;
  const int lane = threadIdx.x;
  const float4* base = reinterpret_cast<const float4*>(sites) + (size_t)b * 1024;

  float4 v[16];
#pragma unroll
  for (int s = 0; s < 16; ++s) v[s] = base[s * 64 + lane];

  // whole bipartition partials
  float aw[64];
#pragma unroll
  for (int i = 0; i < 8; ++i) {
#pragma unroll
    for (int j = 0; j < 8; ++j) {
      float4 a = v[i], c = v[8 + j];
      aw[i * 8 + j] =
          fmaf(a.x, c.x, fmaf(a.y, c.y, fmaf(a.z, c.z, a.w * c.w)));
    }
  }
  float cw = reduce_dist_64(aw, lane);  // entry `lane` fully reduced

  // left + right bipartition partials (packed 32)
  float alr[32];
#pragma unroll
  for (int i = 0; i < 4; ++i) {
#pragma unroll
    for (int j = 0; j < 4; ++j) {
      float4 a = v[i], c = v[4 + j];
      alr[i * 4 + j] =
          fmaf(a.x, c.x, fmaf(a.y, c.y, fmaf(a.z, c.z, a.w * c.w)));
      float4 a2 = v[8 + i], c2 = v[12 + j];
      alr[16 + i * 4 + j] =
          fmaf(a2.x, c2.x, fmaf(a2.y, c2.y, fmaf(a2.z, c2.z, a2.w * c2.w)));
    }
  }
  float clr = reduce_dist_32(alr, lane);  // entry (lane&31)

  cmat[(size_t)lane * 8192 + b] = cw;
  if (lane < 32) cmat[(size_t)(64 + lane) * 8192 + b] = clr;
}

// --- Phase 2: eigenvalues + entropies -------------------------------------
// One thread per batch. Coalesced reads of cmat[e][b].
__global__ __launch_bounds__(64) void phi_kernel(
    const float* __restrict__ cmat, float* __restrict__ out) {
  const int b = blockIdx.x * 64 + threadIdx.x;

  // whole: M = C C^T (8x8 symmetric, packed 36)
  float Cw[64];
#pragma unroll
  for (int e = 0; e < 64; ++e) Cw[e] = cmat[(size_t)e * 8192 + b];
  float Mw[36];
#pragma unroll
  for (int i = 0; i < 8; ++i) {
#pragma unroll
    for (int j = i; j < 8; ++j) {
      float acc = 0.0f;
#pragma unroll
      for (int k = 0; k < 8; ++k) acc = fmaf(Cw[i * 8 + k], Cw[j * 8 + k], acc);
      Mw[TI(8, i, j)] = acc;
    }
  }
  jacobi_sweeps<8, 6>(Mw);
  float Sw = entropy_of<8>(Mw);

  float Cl[16];
#pragma unroll
  for (int e = 0; e < 16; ++e) Cl[e] = cmat[(size_t)(64 + e) * 8192 + b];
  float Ml[10];
#pragma unroll
  for (int i = 0; i < 4; ++i) {
#pragma unroll
    for (int j = i; j < 4; ++j) {
      float acc = 0.0f;
#pragma unroll
      for (int k = 0; k < 4; ++k) acc = fmaf(Cl[i * 4 + k], Cl[j * 4 + k], acc);
      Ml[TI(4, i, j)] = acc;
    }
  }
  jacobi_sweeps<4, 5>(Ml);
  float Sl = entropy_of<4>(Ml);

  float Cr[16];
#pragma unroll
  for (int e = 0; e < 16; ++e) Cr[e] = cmat[(size_t)(80 + e) * 8192 + b];
  float Mr[10];
#pragma unroll
  for (int i = 0; i < 4; ++i) {
#pragma unroll
    for (int j = i; j < 4; ++j) {
      float acc = 0.0f;
#pragma unroll
      for (int k = 0; k < 4; ++k) acc = fmaf(Cr[i * 4 + k], Cr[j * 4 + k], acc);
      Mr[TI(4, i, j)] = acc;
    }
  }
  jacobi_sweeps<4, 5>(Mr);
  float Sr = entropy_of<4>(Mr);

  out[b] = fmaxf(Sw - Sl - Sr, 0.0f);
}

extern "C" void kernel_launch(void* const* d_in, const int* in_sizes, int n_in,
                              void* d_out, int out_size, void* d_ws, size_t ws_size,
                              hipStream_t stream) {
  const float* sites = (const float*)d_in[0];   // [8192, 16, 256] f32
  float* out = (float*)d_out;                   // [8192] f32
  float* cmat = (float*)d_ws;                   // needs 96*8192*4 = 3 MiB

  corr_kernel<<<8192, 64, 0, stream>>>(sites, cmat);
  phi_kernel<<<128, 64, 0, stream>>>(cmat, out);
}

// Round 2
// 212.915 us; speedup vs baseline: 1.0328x; 1.0328x over previous
//
#include <hip/hip_runtime.h>
#include <math.h>

#define DEV __device__ __forceinline__

DEV float rcp_fast(float x) { return __builtin_amdgcn_rcpf(x); }
DEV float rsq_fast(float x) { return __builtin_amdgcn_rsqf(x); }

// packed upper-triangle index for NxN symmetric, requires i<=j
__host__ __device__ constexpr int TI(int n, int i, int j) {
  return n * i - (i * (i - 1)) / 2 + (j - i);
}

template <int N>
DEV float& sym_at(float (&a)[N * (N + 1) / 2], int i, int j) {
  return (i <= j) ? a[TI(N, i, j)] : a[TI(N, j, i)];
}

// --- branchless rotation params + exact diagonal-block update -------------
// Convention: new_p = c*old_p - s*old_q ; new_q = s*old_p + c*old_q
template <int N>
DEV void pivot_params(float (&a)[N * (N + 1) / 2], int p, int q,
                      float& c_out, float& s_out) {
  float apq = a[TI(N, p, q)];
  float app = a[TI(N, p, p)];
  float aqq = a[TI(N, q, q)];
  float h = aqq - app;
  float tw = apq + apq;
  float den = fabsf(h) + sqrtf(fmaf(h, h, tw * tw)) + 1e-37f;
  float t = tw * rcp_fast(den);
  t = (h < 0.0f) ? -t : t;
  float c = rsq_fast(fmaf(t, t, 1.0f));
  float s = t * c;
  c_out = c;
  s_out = s;
  a[TI(N, p, p)] = fmaf(-t, apq, app);  // exact: own 2x2 block is diagonalized
  a[TI(N, q, q)] = fmaf( t, apq, aqq);
  a[TI(N, p, q)] = 0.0f;
}

// cross-block update: B' = Ja^T B Jb for pairs a=(pa,qa), b=(pb,qb)
template <int N>
DEV void cross_update(float (&a)[N * (N + 1) / 2], int pa, int qa, int pb,
                      int qb, float ca, float sa, float cb, float sb) {
  float w = sym_at<N>(a, pa, pb), x = sym_at<N>(a, pa, qb);
  float y = sym_at<N>(a, qa, pb), z = sym_at<N>(a, qa, qb);
  float w1 = fmaf(ca, w, -sa * y), x1 = fmaf(ca, x, -sa * z);
  float y1 = fmaf(sa, w,  ca * y), z1 = fmaf(sa, x,  ca * z);
  sym_at<N>(a, pa, pb) = fmaf(cb, w1, -sb * x1);
  sym_at<N>(a, pa, qb) = fmaf(sb, w1,  cb * x1);
  sym_at<N>(a, qa, pb) = fmaf(cb, y1, -sb * z1);
  sym_at<N>(a, qa, qb) = fmaf(sb, y1,  cb * z1);
}

// Parallel-ordering Jacobi, 8x8: 7 rounds/sweep, 4 disjoint pivots per round
// (independent transcendental chains -> 4x ILP vs cyclic order).
template <int SWEEPS>
DEV void pjacobi8(float (&a)[36]) {
  constexpr int P[7][4][2] = {
      {{0, 7}, {1, 6}, {2, 5}, {3, 4}}, {{0, 1}, {2, 7}, {3, 6}, {4, 5}},
      {{0, 2}, {1, 3}, {4, 7}, {5, 6}}, {{0, 3}, {2, 4}, {1, 5}, {6, 7}},
      {{0, 4}, {3, 5}, {2, 6}, {1, 7}}, {{0, 5}, {4, 6}, {3, 7}, {1, 2}},
      {{0, 6}, {5, 7}, {1, 4}, {2, 3}}};
  for (int sw = 0; sw < SWEEPS; ++sw) {
#pragma unroll
    for (int r = 0; r < 7; ++r) {
      float cc[4], ss[4];
#pragma unroll
      for (int u = 0; u < 4; ++u)
        pivot_params<8>(a, P[r][u][0], P[r][u][1], cc[u], ss[u]);
#pragma unroll
      for (int u = 0; u < 4; ++u) {
#pragma unroll
        for (int v = u + 1; v < 4; ++v) {
          cross_update<8>(a, P[r][u][0], P[r][u][1], P[r][v][0], P[r][v][1],
                          cc[u], ss[u], cc[v], ss[v]);
        }
      }
    }
  }
}

// Two independent 4x4 problems advanced in lockstep (2x ILP).
template <int SWEEPS>
DEV void pjacobi4x2(float (&a)[10], float (&b)[10]) {
  constexpr int P[3][2][2] = {
      {{0, 3}, {1, 2}}, {{0, 1}, {2, 3}}, {{0, 2}, {1, 3}}};
  for (int sw = 0; sw < SWEEPS; ++sw) {
#pragma unroll
    for (int r = 0; r < 3; ++r) {
      float ca0, sa0, ca1, sa1, cb0, sb0, cb1, sb1;
      pivot_params<4>(a, P[r][0][0], P[r][0][1], ca0, sa0);
      pivot_params<4>(b, P[r][0][0], P[r][0][1], cb0, sb0);
      pivot_params<4>(a, P[r][1][0], P[r][1][1], ca1, sa1);
      pivot_params<4>(b, P[r][1][0], P[r][1][1], cb1, sb1);
      cross_update<4>(a, P[r][0][0], P[r][0][1], P[r][1][0], P[r][1][1], ca0,
                      sa0, ca1, sa1);
      cross_update<4>(b, P[r][0][0], P[r][0][1], P[r][1][0], P[r][1][1], cb0,
                      sb0, cb1, sb1);
    }
  }
}

// entropy mirroring reference EPS placement:
// s_sq = lam + 1e-10 ; p = s_sq/sum ; H = -sum p*log(p + 1e-10)
template <int N>
DEV float entropy_of(const float (&a)[N * (N + 1) / 2]) {
  float lam[N];
  float sum = 0.0f;
#pragma unroll
  for (int i = 0; i < N; ++i) {
    float l = fmaxf(a[TI(N, i, i)], 0.0f) + 1e-10f;
    lam[i] = l;
    sum += l;
  }
  float inv = 1.0f / sum;
  float H = 0.0f;
#pragma unroll
  for (int i = 0; i < N; ++i) {
    float p = lam[i] * inv;
    H = fmaf(p, __logf(p + 1e-10f), H);
  }
  return -H;
}

// --- cross-lane reduction with distribution -------------------------------
DEV float reduce_dist_64(float (&cur)[64], int lane) {
#pragma unroll
  for (int d = 0; d < 6; ++d) {
    const int dist = 1 << d;
    const int up = (lane >> d) & 1;
#pragma unroll
    for (int m = 0; m < (64 >> (d + 1)); ++m) {
      float snd = up ? cur[2 * m]     : cur[2 * m + 1];
      float kp  = up ? cur[2 * m + 1] : cur[2 * m];
      float r = __shfl_xor(snd, dist, 64);
      cur[m] = kp + r;
    }
  }
  return cur[0];
}

DEV float reduce_dist_32(float (&cur)[32], int lane) {
#pragma unroll
  for (int d = 0; d < 5; ++d) {
    const int dist = 1 << d;
    const int up = (lane >> d) & 1;
#pragma unroll
    for (int m = 0; m < (32 >> (d + 1)); ++m) {
      float snd = up ? cur[2 * m]     : cur[2 * m + 1];
      float kp  = up ? cur[2 * m + 1] : cur[2 * m];
      float r = __shfl_xor(snd, dist, 64);
      cur[m] = kp + r;
    }
  }
  float v = cur[0];
  v += __shfl_xor(v, 32, 64);
  return v;
}

// --- Phase 1: correlation matrices (one wave per batch) -------------------
// cmat[e * 8192 + b]: e in [0,64) C_whole (i*8+j); [64,80) C_left; [80,96) C_right
__global__ __launch_bounds__(64) void corr_kernel(
    const float* __restrict__ sites, float* __restrict__ cmat) {
  const int b = blockIdx.x;
  const int lane = threadIdx.x;
  const float4* base = reinterpret_cast<const float4*>(sites) + (size_t)b * 1024;

  float4 v[16];
#pragma unroll
  for (int s = 0; s < 16; ++s) v[s] = base[s * 64 + lane];

  float aw[64];
#pragma unroll
  for (int i = 0; i < 8; ++i) {
#pragma unroll
    for (int j = 0; j < 8; ++j) {
      float4 a = v[i], c = v[8 + j];
      aw[i * 8 + j] =
          fmaf(a.x, c.x, fmaf(a.y, c.y, fmaf(a.z, c.z, a.w * c.w)));
    }
  }
  float cw = reduce_dist_64(aw, lane);

  float alr[32];
#pragma unroll
  for (int i = 0; i < 4; ++i) {
#pragma unroll
    for (int j = 0; j < 4; ++j) {
      float4 a = v[i], c = v[4 + j];
      alr[i * 4 + j] =
          fmaf(a.x, c.x, fmaf(a.y, c.y, fmaf(a.z, c.z, a.w * c.w)));
      float4 a2 = v[8 + i], c2 = v[12 + j];
      alr[16 + i * 4 + j] =
          fmaf(a2.x, c2.x, fmaf(a2.y, c2.y, fmaf(a2.z, c2.z, a2.w * c2.w)));
    }
  }
  float clr = reduce_dist_32(alr, lane);

  cmat[(size_t)lane * 8192 + b] = cw;
  if (lane < 32) cmat[(size_t)(64 + lane) * 8192 + b] = clr;
}

// --- Phase 2: eigenvalues + entropies (one thread per batch) --------------
__global__ __launch_bounds__(64) void phi_kernel(
    const float* __restrict__ cmat, float* __restrict__ out) {
  const int b = blockIdx.x * 64 + threadIdx.x;

  float Cw[64];
#pragma unroll
  for (int e = 0; e < 64; ++e) Cw[e] = cmat[(size_t)e * 8192 + b];
  float Mw[36];
#pragma unroll
  for (int i = 0; i < 8; ++i) {
#pragma unroll
    for (int j = i; j < 8; ++j) {
      float acc = 0.0f;
#pragma unroll
      for (int k = 0; k < 8; ++k) acc = fmaf(Cw[i * 8 + k], Cw[j * 8 + k], acc);
      Mw[TI(8, i, j)] = acc;
    }
  }

  float Cl[16], Cr[16];
#pragma unroll
  for (int e = 0; e < 16; ++e) Cl[e] = cmat[(size_t)(64 + e) * 8192 + b];
#pragma unroll
  for (int e = 0; e < 16; ++e) Cr[e] = cmat[(size_t)(80 + e) * 8192 + b];
  float Ml[10], Mr[10];
#pragma unroll
  for (int i = 0; i < 4; ++i) {
#pragma unroll
    for (int j = i; j < 4; ++j) {
      float accl = 0.0f, accr = 0.0f;
#pragma unroll
      for (int k = 0; k < 4; ++k) {
        accl = fmaf(Cl[i * 4 + k], Cl[j * 4 + k], accl);
        accr = fmaf(Cr[i * 4 + k], Cr[j * 4 + k], accr);
      }
      Ml[TI(4, i, j)] = accl;
      Mr[TI(4, i, j)] = accr;
    }
  }

  pjacobi8<5>(Mw);
  pjacobi4x2<4>(Ml, Mr);

  float Sw = entropy_of<8>(Mw);
  float Sl = entropy_of<4>(Ml);
  float Sr = entropy_of<4>(Mr);

  out[b] = fmaxf(Sw - Sl - Sr, 0.0f);
}

extern "C" void kernel_launch(void* const* d_in, const int* in_sizes, int n_in,
                              void* d_out, int out_size, void* d_ws, size_t ws_size,
                              hipStream_t stream) {
  const float* sites = (const float*)d_in[0];   // [8192, 16, 256] f32
  float* out = (float*)d_out;                   // [8192] f32
  float* cmat = (float*)d_ws;                   // 96*8192*4 = 3 MiB used

  corr_kernel<<<8192, 64, 0, stream>>>(sites, cmat);
  phi_kernel<<<128, 64, 0, stream>>>(cmat, out);
}

// Round 3
// 203.496 us; speedup vs baseline: 1.0806x; 1.0463x over previous
//
#include <hip/hip_runtime.h>
#include <math.h>

#define DEV __device__ __forceinline__

DEV float rcp_fast(float x) { return __builtin_amdgcn_rcpf(x); }
DEV float rsq_fast(float x) { return __builtin_amdgcn_rsqf(x); }

// packed upper-triangle index for NxN symmetric, requires i<=j
__host__ __device__ constexpr int TI(int n, int i, int j) {
  return n * i - (i * (i - 1)) / 2 + (j - i);
}

template <int N>
DEV float& sym_at(float (&a)[N * (N + 1) / 2], int i, int j) {
  return (i <= j) ? a[TI(N, i, j)] : a[TI(N, j, i)];
}

// --- branchless rotation params + exact diagonal-block update -------------
template <int N>
DEV void pivot_params(float (&a)[N * (N + 1) / 2], int p, int q,
                      float& c_out, float& s_out) {
  float apq = a[TI(N, p, q)];
  float app = a[TI(N, p, p)];
  float aqq = a[TI(N, q, q)];
  float h = aqq - app;
  float tw = apq + apq;
  float den = fabsf(h) + sqrtf(fmaf(h, h, tw * tw)) + 1e-37f;
  float t = tw * rcp_fast(den);
  t = (h < 0.0f) ? -t : t;
  float c = rsq_fast(fmaf(t, t, 1.0f));
  float s = t * c;
  c_out = c;
  s_out = s;
  a[TI(N, p, p)] = fmaf(-t, apq, app);
  a[TI(N, q, q)] = fmaf( t, apq, aqq);
  a[TI(N, p, q)] = 0.0f;
}

template <int N>
DEV void cross_update(float (&a)[N * (N + 1) / 2], int pa, int qa, int pb,
                      int qb, float ca, float sa, float cb, float sb) {
  float w = sym_at<N>(a, pa, pb), x = sym_at<N>(a, pa, qb);
  float y = sym_at<N>(a, qa, pb), z = sym_at<N>(a, qa, qb);
  float w1 = fmaf(ca, w, -sa * y), x1 = fmaf(ca, x, -sa * z);
  float y1 = fmaf(sa, w,  ca * y), z1 = fmaf(sa, x,  ca * z);
  sym_at<N>(a, pa, pb) = fmaf(cb, w1, -sb * x1);
  sym_at<N>(a, pa, qb) = fmaf(sb, w1,  cb * x1);
  sym_at<N>(a, qa, pb) = fmaf(cb, y1, -sb * z1);
  sym_at<N>(a, qa, qb) = fmaf(sb, y1,  cb * z1);
}

// Parallel-ordering Jacobi 8x8: 7 rounds/sweep, 4 disjoint pivots per round.
template <int SWEEPS>
DEV void pjacobi8(float (&a)[36]) {
  constexpr int P[7][4][2] = {
      {{0, 7}, {1, 6}, {2, 5}, {3, 4}}, {{0, 1}, {2, 7}, {3, 6}, {4, 5}},
      {{0, 2}, {1, 3}, {4, 7}, {5, 6}}, {{0, 3}, {2, 4}, {1, 5}, {6, 7}},
      {{0, 4}, {3, 5}, {2, 6}, {1, 7}}, {{0, 5}, {4, 6}, {3, 7}, {1, 2}},
      {{0, 6}, {5, 7}, {1, 4}, {2, 3}}};
  for (int sw = 0; sw < SWEEPS; ++sw) {
#pragma unroll
    for (int r = 0; r < 7; ++r) {
      float cc[4], ss[4];
#pragma unroll
      for (int u = 0; u < 4; ++u)
        pivot_params<8>(a, P[r][u][0], P[r][u][1], cc[u], ss[u]);
#pragma unroll
      for (int u = 0; u < 4; ++u) {
#pragma unroll
        for (int v = u + 1; v < 4; ++v) {
          cross_update<8>(a, P[r][u][0], P[r][u][1], P[r][v][0], P[r][v][1],
                          cc[u], ss[u], cc[v], ss[v]);
        }
      }
    }
  }
}

// Two independent 4x4 problems in lockstep (2x ILP).
template <int SWEEPS>
DEV void pjacobi4x2(float (&a)[10], float (&b)[10]) {
  constexpr int P[3][2][2] = {
      {{0, 3}, {1, 2}}, {{0, 1}, {2, 3}}, {{0, 2}, {1, 3}}};
  for (int sw = 0; sw < SWEEPS; ++sw) {
#pragma unroll
    for (int r = 0; r < 3; ++r) {
      float ca0, sa0, ca1, sa1, cb0, sb0, cb1, sb1;
      pivot_params<4>(a, P[r][0][0], P[r][0][1], ca0, sa0);
      pivot_params<4>(b, P[r][0][0], P[r][0][1], cb0, sb0);
      pivot_params<4>(a, P[r][1][0], P[r][1][1], ca1, sa1);
      pivot_params<4>(b, P[r][1][0], P[r][1][1], cb1, sb1);
      cross_update<4>(a, P[r][0][0], P[r][0][1], P[r][1][0], P[r][1][1], ca0,
                      sa0, ca1, sa1);
      cross_update<4>(b, P[r][0][0], P[r][0][1], P[r][1][0], P[r][1][1], cb0,
                      sb0, cb1, sb1);
    }
  }
}

// entropy mirroring reference EPS placement
template <int N>
DEV float entropy_of(const float (&a)[N * (N + 1) / 2]) {
  float lam[N];
  float sum = 0.0f;
#pragma unroll
  for (int i = 0; i < N; ++i) {
    float l = fmaxf(a[TI(N, i, i)], 0.0f) + 1e-10f;
    lam[i] = l;
    sum += l;
  }
  float inv = 1.0f / sum;
  float H = 0.0f;
#pragma unroll
  for (int i = 0; i < N; ++i) {
    float p = lam[i] * inv;
    H = fmaf(p, __logf(p + 1e-10f), H);
  }
  return -H;
}

// --- cross-lane reduction with distribution -------------------------------
DEV float reduce_dist_64(float (&cur)[64], int lane) {
#pragma unroll
  for (int d = 0; d < 6; ++d) {
    const int dist = 1 << d;
    const int up = (lane >> d) & 1;
#pragma unroll
    for (int m = 0; m < (64 >> (d + 1)); ++m) {
      float snd = up ? cur[2 * m]     : cur[2 * m + 1];
      float kp  = up ? cur[2 * m + 1] : cur[2 * m];
      float r = __shfl_xor(snd, dist, 64);
      cur[m] = kp + r;
    }
  }
  return cur[0];
}

DEV float reduce_dist_32(float (&cur)[32], int lane) {
#pragma unroll
  for (int d = 0; d < 5; ++d) {
    const int dist = 1 << d;
    const int up = (lane >> d) & 1;
#pragma unroll
    for (int m = 0; m < (32 >> (d + 1)); ++m) {
      float snd = up ? cur[2 * m]     : cur[2 * m + 1];
      float kp  = up ? cur[2 * m + 1] : cur[2 * m];
      float r = __shfl_xor(snd, dist, 64);
      cur[m] = kp + r;
    }
  }
  float v = cur[0];
  v += __shfl_xor(v, 32, 64);
  return v;
}

// --- Phase 1: correlation matrices (one wave per batch) -------------------
// NEW layout: cmat[b * 96 + e]  (row per batch -> fully coalesced stores)
//   e in [0,64):  C_whole[i][j], e = i*8+j
//   e in [64,80): C_left;  e in [80,96): C_right
__global__ __launch_bounds__(64) void corr_kernel(
    const float* __restrict__ sites, float* __restrict__ cmat) {
  const int b = blockIdx.x;
  const int lane = threadIdx.x;
  const float4* base = reinterpret_cast<const float4*>(sites) + (size_t)b * 1024;

  float4 v[16];
#pragma unroll
  for (int s = 0; s < 16; ++s) v[s] = base[s * 64 + lane];

  float aw[64];
#pragma unroll
  for (int i = 0; i < 8; ++i) {
#pragma unroll
    for (int j = 0; j < 8; ++j) {
      float4 a = v[i], c = v[8 + j];
      aw[i * 8 + j] =
          fmaf(a.x, c.x, fmaf(a.y, c.y, fmaf(a.z, c.z, a.w * c.w)));
    }
  }
  float cw = reduce_dist_64(aw, lane);

  float alr[32];
#pragma unroll
  for (int i = 0; i < 4; ++i) {
#pragma unroll
    for (int j = 0; j < 4; ++j) {
      float4 a = v[i], c = v[4 + j];
      alr[i * 4 + j] =
          fmaf(a.x, c.x, fmaf(a.y, c.y, fmaf(a.z, c.z, a.w * c.w)));
      float4 a2 = v[8 + i], c2 = v[12 + j];
      alr[16 + i * 4 + j] =
          fmaf(a2.x, c2.x, fmaf(a2.y, c2.y, fmaf(a2.z, c2.z, a2.w * c2.w)));
    }
  }
  float clr = reduce_dist_32(alr, lane);

  float* row = cmat + (size_t)b * 96;
  row[lane] = cw;                        // e = 0..63, contiguous 256B
  if (lane < 32) row[64 + lane] = clr;   // e = 64..95, contiguous 128B
}

// --- Phase 2: eigenvalues + entropies -------------------------------------
// Block = 64 threads = 64 batches. Cooperative coalesced float4 load of the
// 64 rows (96 floats each) into LDS (rows padded to 25 float4), then each
// thread works on its own row.
__global__ __launch_bounds__(64) void phi_kernel(
    const float* __restrict__ cmat, float* __restrict__ out) {
  __shared__ float4 lds[64 * 25];
  const int t = threadIdx.x;
  const int b0 = blockIdx.x * 64;

  const float4* src = reinterpret_cast<const float4*>(cmat) + (size_t)b0 * 24;
#pragma unroll
  for (int r = 0; r < 24; ++r) {
    int q = r * 64 + t;          // flat float4 index within the block's tile
    float4 val = src[q];
    int bl = q / 24;             // local batch row
    int e4 = q - bl * 24;        // float4 column
    lds[bl * 25 + e4] = val;
  }
  __syncthreads();

  const float4* myrow = &lds[t * 25];
  float Cw[64], Cl[16], Cr[16];
#pragma unroll
  for (int j = 0; j < 16; ++j) {
    float4 f = myrow[j];
    Cw[4 * j] = f.x; Cw[4 * j + 1] = f.y; Cw[4 * j + 2] = f.z; Cw[4 * j + 3] = f.w;
  }
#pragma unroll
  for (int j = 0; j < 4; ++j) {
    float4 f = myrow[16 + j];
    Cl[4 * j] = f.x; Cl[4 * j + 1] = f.y; Cl[4 * j + 2] = f.z; Cl[4 * j + 3] = f.w;
    float4 g = myrow[20 + j];
    Cr[4 * j] = g.x; Cr[4 * j + 1] = g.y; Cr[4 * j + 2] = g.z; Cr[4 * j + 3] = g.w;
  }

  float Mw[36];
#pragma unroll
  for (int i = 0; i < 8; ++i) {
#pragma unroll
    for (int j = i; j < 8; ++j) {
      float acc = 0.0f;
#pragma unroll
      for (int k = 0; k < 8; ++k) acc = fmaf(Cw[i * 8 + k], Cw[j * 8 + k], acc);
      Mw[TI(8, i, j)] = acc;
    }
  }
  float Ml[10], Mr[10];
#pragma unroll
  for (int i = 0; i < 4; ++i) {
#pragma unroll
    for (int j = i; j < 4; ++j) {
      float accl = 0.0f, accr = 0.0f;
#pragma unroll
      for (int k = 0; k < 4; ++k) {
        accl = fmaf(Cl[i * 4 + k], Cl[j * 4 + k], accl);
        accr = fmaf(Cr[i * 4 + k], Cr[j * 4 + k], accr);
      }
      Ml[TI(4, i, j)] = accl;
      Mr[TI(4, i, j)] = accr;
    }
  }

  pjacobi8<4>(Mw);
  pjacobi4x2<3>(Ml, Mr);

  float Sw = entropy_of<8>(Mw);
  float Sl = entropy_of<4>(Ml);
  float Sr = entropy_of<4>(Mr);

  out[b0 + t] = fmaxf(Sw - Sl - Sr, 0.0f);
}

extern "C" void kernel_launch(void* const* d_in, const int* in_sizes, int n_in,
                              void* d_out, int out_size, void* d_ws, size_t ws_size,
                              hipStream_t stream) {
  const float* sites = (const float*)d_in[0];   // [8192, 16, 256] f32
  float* out = (float*)d_out;                   // [8192] f32
  float* cmat = (float*)d_ws;                   // 8192*96*4 = 3 MiB used

  corr_kernel<<<8192, 64, 0, stream>>>(sites, cmat);
  phi_kernel<<<128, 64, 0, stream>>>(cmat, out);
}